// Round 6
// baseline (158.488 us; speedup 1.0000x reference)
//
#include <hip/hip_runtime.h>
#include <hip/hip_bf16.h>
#include <hip/hip_cooperative_groups.h>

namespace cg = cooperative_groups;

// out = (4096 * (x @ Wv)) @ w_proj + b_proj   [softmax rows sum to 1 =>
// head_w == N_NODES exactly; adj, w_q, w_k never affect the output]
// Wv[d][c=h*128+hd] = w_qkv[2][h][d][hd].  All global tensors fp32.
//
// R6: ONE cooperative kernel (256 blocks = 1/CU, 256 thr):
//   phase 1: all waves cvt x->xb bf16; wave 0 also builds one 32x32 tile of
//            Mt[o][d] = 4096*(Wv@Wp)^T (bf16) via MFMA.
//   grid.sync()
//   phase 2: out = xb @ Mt^T + bias (validated R5 gemm, blockIdx remapped).
// Removes 2 of 3 dispatch gaps; per-iteration harness poison/restore
// (~110 us: 256MB ws fill at 41 us + input restores + gaps) dominates dur_us.

constexpr int NNODES = 4096;
constexpr int DIM = 512;

typedef __bf16 bf16x8 __attribute__((ext_vector_type(8)));
typedef float f32x4 __attribute__((ext_vector_type(4)));

__device__ __forceinline__ bf16x8 cvt8(const float* p) {
  const f32x4 lo = *(const f32x4*)p;
  const f32x4 hi = *(const f32x4*)(p + 4);
  bf16x8 r;
#pragma unroll
  for (int j = 0; j < 4; ++j) { r[j] = (__bf16)lo[j]; r[4 + j] = (__bf16)hi[j]; }
  return r;
}

__global__ __launch_bounds__(256) void fused(
    const float* __restrict__ x,
    const float* __restrict__ w_qkv,
    const float* __restrict__ w_proj,
    const float* __restrict__ bias,
    __bf16* __restrict__ Mt,
    __bf16* __restrict__ xb,
    float* __restrict__ out) {
  const int blk = blockIdx.x;
  const int tid = threadIdx.x;
  const int wave = tid >> 6, lane = tid & 63;
  const int ln = lane & 15, q = lane >> 4;

  // ---- Phase 1a: xb = (bf16)x.  262144 vec8 chunks / 65536 threads = 4 each.
  {
    const int g = blk * 256 + tid;
#pragma unroll
    for (int i = 0; i < 4; ++i) {
      const size_t v = (size_t)g + (size_t)i * 65536;
      *(bf16x8*)&xb[v * 8] = cvt8(&x[v * 8]);
    }
  }

  // ---- Phase 1b: wave 0 builds Mt tile blk: rows o in [m0,m0+32), cols d.
  if (wave == 0) {
    const int m0 = (blk >> 4) * 32;   // o
    const int n0 = (blk & 15) * 32;   // d
    const float* __restrict__ wv = w_qkv + 2 * 4 * DIM * 128;  // v slice
    f32x4 acc[2][2] = {};
#pragma unroll
    for (int k0 = 0; k0 < DIM; k0 += 32) {   // k = c = h*128+hd
      const int h = k0 >> 7, hb = k0 & 127;
      bf16x8 af[2], bf[2];
#pragma unroll
      for (int mi = 0; mi < 2; ++mi) {
        float raw[8];
#pragma unroll
        for (int j = 0; j < 8; ++j)
          raw[j] = w_proj[(k0 + q * 8 + j) * DIM + (m0 + mi * 16 + ln)];
#pragma unroll
        for (int j = 0; j < 8; ++j) af[mi][j] = (__bf16)raw[j];
      }
#pragma unroll
      for (int ni = 0; ni < 2; ++ni)
        bf[ni] = cvt8(&wv[((size_t)h * DIM + (n0 + ni * 16 + ln)) * 128 + hb + q * 8]);
#pragma unroll
      for (int mi = 0; mi < 2; ++mi)
#pragma unroll
        for (int ni = 0; ni < 2; ++ni)
          acc[mi][ni] = __builtin_amdgcn_mfma_f32_16x16x32_bf16(
              af[mi], bf[ni], acc[mi][ni], 0, 0, 0);
    }
    // D layout: col = lane&15, row = (lane>>4)*4 + reg
#pragma unroll
    for (int mi = 0; mi < 2; ++mi)
#pragma unroll
      for (int ni = 0; ni < 2; ++ni)
#pragma unroll
        for (int r = 0; r < 4; ++r) {
          const int o = m0 + mi * 16 + q * 4 + r;
          const int d = n0 + ni * 16 + ln;
          Mt[o * DIM + d] = (__bf16)(acc[mi][ni][r] * (float)NNODES);
        }
  }

  // ---- All Mt/xb writes visible grid-wide past this point.
  cg::this_grid().sync();

  // ---- Phase 2: out[b][o] = sum_d xb[b][d]*Mt[o][d] + bias[o].
  // 4 waves: wave tile 32(b) x 64(o); block tile 64 x 128.
  const int m0 = (blk >> 2) * 64 + (wave >> 1) * 32;   // b rows  (64 row-tiles)
  const int n0 = (blk & 3) * 128 + (wave & 1) * 64;    // o cols  (4 col-groups)

  f32x4 acc[2][4] = {};
#pragma unroll 4
  for (int k0 = 0; k0 < DIM; k0 += 32) {
    bf16x8 af[2], bf[4];
#pragma unroll
    for (int mi = 0; mi < 2; ++mi)
      af[mi] = *(const bf16x8*)&xb[(size_t)(m0 + mi * 16 + ln) * DIM + k0 + q * 8];
#pragma unroll
    for (int ni = 0; ni < 4; ++ni)
      bf[ni] = *(const bf16x8*)&Mt[(size_t)(n0 + ni * 16 + ln) * DIM + k0 + q * 8];
#pragma unroll
    for (int mi = 0; mi < 2; ++mi)
#pragma unroll
      for (int ni = 0; ni < 4; ++ni)
        acc[mi][ni] = __builtin_amdgcn_mfma_f32_16x16x32_bf16(
            af[mi], bf[ni], acc[mi][ni], 0, 0, 0);
  }

#pragma unroll
  for (int ni = 0; ni < 4; ++ni) {
    const int o = n0 + ni * 16 + ln;
    const float bj = bias[o];
#pragma unroll
    for (int mi = 0; mi < 2; ++mi)
#pragma unroll
      for (int r = 0; r < 4; ++r) {
        const int b = m0 + mi * 16 + q * 4 + r;
        out[(size_t)b * DIM + o] = acc[mi][ni][r] + bj;
      }
  }
}

extern "C" void kernel_launch(void* const* d_in, const int* in_sizes, int n_in,
                              void* d_out, int out_size, void* d_ws, size_t ws_size,
                              hipStream_t stream) {
  const float* x      = (const float*)d_in[0];
  // d_in[1] = adj — irrelevant (softmax rows sum to 1), never read
  const float* w_qkv  = (const float*)d_in[2];
  const float* w_proj = (const float*)d_in[3];
  const float* b_proj = (const float*)d_in[4];
  __bf16* Mt = (__bf16*)d_ws;                          // 512 KB
  __bf16* xb = (__bf16*)((char*)d_ws + DIM * DIM * 2); // 4 MB, 16B-aligned
  float* out = (float*)d_out;                          // 4096*512 fp32

  void* args[] = {(void*)&x, (void*)&w_qkv, (void*)&w_proj, (void*)&b_proj,
                  (void*)&Mt, (void*)&xb, (void*)&out};
  hipLaunchCooperativeKernel((void*)fused, dim3(256), dim3(256), args, 0, stream);
}

// Round 7
// 129.187 us; speedup vs baseline: 1.2268x; 1.2268x over previous
//
#include <hip/hip_runtime.h>
#include <hip/hip_bf16.h>

// out = (4096 * (x @ Wv)) @ w_proj + b_proj   [softmax rows sum to 1 =>
// head_w == N_NODES exactly; adj, w_q, w_k never affect the output]
// Wv[d][c=h*128+hd] = w_qkv[2][h][d][hd].  All global tensors fp32.
//
// R7: back to the R5 multi-kernel shape (R6's cooperative fusion cost 30 µs:
// 1 block/CU + grid.sync killed latency hiding). Two LDS-free MFMA kernels:
//  1) build_Mt: Mt[o][d] = 4096*(Wv@Wp)^T, bf16 in d_ws.
//  2) gemm_out: out = x @ Mt^T + b; 4-wave blocks, 64x128 tile; A-frags
//     cvt'd inline from fp32 x (no xb round-trip), B-frags 16B bf16 loads.
// dur_us is dominated by fixed harness poison/restore (~110 µs; the 256 MB
// d_ws fill alone is 41 µs at 81% HBM peak).

constexpr int NNODES = 4096;
constexpr int DIM = 512;

typedef __bf16 bf16x8 __attribute__((ext_vector_type(8)));
typedef float f32x4 __attribute__((ext_vector_type(4)));

__device__ __forceinline__ bf16x8 cvt8(const float* p) {
  const f32x4 lo = *(const f32x4*)p;
  const f32x4 hi = *(const f32x4*)(p + 4);
  bf16x8 r;
#pragma unroll
  for (int j = 0; j < 4; ++j) { r[j] = (__bf16)lo[j]; r[4 + j] = (__bf16)hi[j]; }
  return r;
}

// ---------------------------------------------------------------------------
// Kernel 1: Mt[o][d] = 4096 * sum_c Wp[c][o] * Wv[d][c], bf16.
// One wave per 32(o) x 32(d) tile. Grid 16x16 = 256 single-wave blocks.
// ---------------------------------------------------------------------------
__global__ __launch_bounds__(64) void build_Mt(
    const float* __restrict__ w_qkv,
    const float* __restrict__ w_proj,
    __bf16* __restrict__ Mt) {
  const int lane = threadIdx.x;
  const int ln = lane & 15, q = lane >> 4;
  const int m0 = blockIdx.y * 32;   // o rows of Mt
  const int n0 = blockIdx.x * 32;   // d cols of Mt
  const float* __restrict__ wv = w_qkv + 2 * 4 * DIM * 128;  // v slice

  f32x4 acc[2][2] = {};

#pragma unroll
  for (int k0 = 0; k0 < DIM; k0 += 32) {   // k = c = h*128+hd
    const int h = k0 >> 7, hb = k0 & 127;
    bf16x8 af[2], bf[2];
#pragma unroll
    for (int mi = 0; mi < 2; ++mi) {
      float raw[8];
#pragma unroll
      for (int j = 0; j < 8; ++j)
        raw[j] = w_proj[(k0 + q * 8 + j) * DIM + (m0 + mi * 16 + ln)];
#pragma unroll
      for (int j = 0; j < 8; ++j) af[mi][j] = (__bf16)raw[j];
    }
#pragma unroll
    for (int ni = 0; ni < 2; ++ni)
      bf[ni] = cvt8(&wv[((size_t)h * DIM + (n0 + ni * 16 + ln)) * 128 + hb + q * 8]);
#pragma unroll
    for (int mi = 0; mi < 2; ++mi)
#pragma unroll
      for (int ni = 0; ni < 2; ++ni)
        acc[mi][ni] = __builtin_amdgcn_mfma_f32_16x16x32_bf16(
            af[mi], bf[ni], acc[mi][ni], 0, 0, 0);
  }

  // D layout: col = lane&15, row = (lane>>4)*4 + reg
#pragma unroll
  for (int mi = 0; mi < 2; ++mi)
#pragma unroll
    for (int ni = 0; ni < 2; ++ni)
#pragma unroll
      for (int r = 0; r < 4; ++r) {
        const int o = m0 + mi * 16 + q * 4 + r;
        const int d = n0 + ni * 16 + ln;
        Mt[o * DIM + d] = (__bf16)(acc[mi][ni][r] * (float)NNODES);
      }
}

// ---------------------------------------------------------------------------
// Kernel 2: out[b][o] = sum_d x[b][d] * Mt[o][d] + bias[o], fp32 out.
// 256 threads = 4 waves (2m x 2n); wave tile 32(b) x 64(o); block 64x128.
// Grid (512/128) x (4096/64) = 4 x 64 = 256 blocks, 8 waves/CU.
// Per wave K-iter: 4x dwordx4 (x fp32) + 4x 16B (Mt) loads, 8 MFMAs.
// ---------------------------------------------------------------------------
__global__ __launch_bounds__(256) void gemm_out(
    const float* __restrict__ x,
    const __bf16* __restrict__ Mt,
    const float* __restrict__ bias,
    float* __restrict__ out) {
  const int tid = threadIdx.x;
  const int wave = tid >> 6, lane = tid & 63;
  const int ln = lane & 15, q = lane >> 4;
  const int m0 = blockIdx.y * 64 + (wave >> 1) * 32;   // b rows
  const int n0 = blockIdx.x * 128 + (wave & 1) * 64;   // o cols

  f32x4 acc[2][4] = {};

#pragma unroll 4
  for (int k0 = 0; k0 < DIM; k0 += 32) {
    bf16x8 af[2], bf[4];
#pragma unroll
    for (int mi = 0; mi < 2; ++mi)
      af[mi] = cvt8(&x[(size_t)(m0 + mi * 16 + ln) * DIM + k0 + q * 8]);
#pragma unroll
    for (int ni = 0; ni < 4; ++ni)
      bf[ni] = *(const bf16x8*)&Mt[(size_t)(n0 + ni * 16 + ln) * DIM + k0 + q * 8];
#pragma unroll
    for (int mi = 0; mi < 2; ++mi)
#pragma unroll
      for (int ni = 0; ni < 4; ++ni)
        acc[mi][ni] = __builtin_amdgcn_mfma_f32_16x16x32_bf16(
            af[mi], bf[ni], acc[mi][ni], 0, 0, 0);
  }

#pragma unroll
  for (int ni = 0; ni < 4; ++ni) {
    const int o = n0 + ni * 16 + ln;
    const float bj = bias[o];
#pragma unroll
    for (int mi = 0; mi < 2; ++mi)
#pragma unroll
      for (int r = 0; r < 4; ++r) {
        const int b = m0 + mi * 16 + q * 4 + r;
        out[(size_t)b * DIM + o] = acc[mi][ni][r] + bj;
      }
  }
}

extern "C" void kernel_launch(void* const* d_in, const int* in_sizes, int n_in,
                              void* d_out, int out_size, void* d_ws, size_t ws_size,
                              hipStream_t stream) {
  const float* x      = (const float*)d_in[0];
  // d_in[1] = adj — irrelevant (softmax rows sum to 1), never read
  const float* w_qkv  = (const float*)d_in[2];
  const float* w_proj = (const float*)d_in[3];
  const float* b_proj = (const float*)d_in[4];
  __bf16* Mt = (__bf16*)d_ws;              // 512*512*2 = 512 KB scratch
  float* out = (float*)d_out;              // 4096*512 fp32

  build_Mt<<<dim3(DIM / 32, DIM / 32), 64, 0, stream>>>(w_qkv, w_proj, Mt);
  gemm_out<<<dim3(DIM / 128, NNODES / 64), 256, 0, stream>>>(x, Mt, b_proj, out);
}

// Round 8
// 127.875 us; speedup vs baseline: 1.2394x; 1.0103x over previous
//
#include <hip/hip_runtime.h>
#include <hip/hip_bf16.h>

// out = (4096 * (x @ Wv)) @ w_proj + b_proj   [softmax rows sum to 1 =>
// head_w == N_NODES exactly; adj, w_q, w_k never affect the output]
// Wv[d][c=h*128+hd] = w_qkv[2][h][d][hd].  All global tensors fp32.
//
// R8 = R5 verbatim (measured best: 125.8 µs). Three LDS-free kernels:
//  1) cvt_x: x fp32 -> xb bf16 so gemm A-frags are single 16B loads.
//  2) build_Mt: Mt[o][d] = 4096*(Wv@Wp)^T, bf16 in d_ws.
//  3) gemm_out: out = xb @ Mt^T + b; 4-wave blocks, 64x128 tile.
// A/B history: R6 cooperative fusion +30 µs (1 blk/CU + grid.sync);
// R7 inline-cvt (no xb) +3.4 µs. dur_us is ~90% fixed harness
// poison/restore (256 MB d_ws fill alone = 42 µs at ~80% HBM peak).

constexpr int NNODES = 4096;
constexpr int DIM = 512;

typedef __bf16 bf16x8 __attribute__((ext_vector_type(8)));
typedef float f32x4 __attribute__((ext_vector_type(4)));

__device__ __forceinline__ bf16x8 cvt8(const float* p) {
  const f32x4 lo = *(const f32x4*)p;
  const f32x4 hi = *(const f32x4*)(p + 4);
  bf16x8 r;
#pragma unroll
  for (int j = 0; j < 4; ++j) { r[j] = (__bf16)lo[j]; r[4 + j] = (__bf16)hi[j]; }
  return r;
}

// ---------------------------------------------------------------------------
// Kernel 0: xb = (bf16)x, 8 elems/thread.
// ---------------------------------------------------------------------------
__global__ __launch_bounds__(256) void cvt_x(
    const float* __restrict__ x, __bf16* __restrict__ xb) {
  const int t = blockIdx.x * 256 + threadIdx.x;
  *(bf16x8*)&xb[(size_t)t * 8] = cvt8(&x[(size_t)t * 8]);
}

// ---------------------------------------------------------------------------
// Kernel 1: Mt[o][d] = 4096 * sum_c Wp[c][o] * Wv[d][c], bf16.
// One wave per 32(o) x 32(d) tile. Grid 16x16 = 256 single-wave blocks.
// ---------------------------------------------------------------------------
__global__ __launch_bounds__(64) void build_Mt(
    const float* __restrict__ w_qkv,
    const float* __restrict__ w_proj,
    __bf16* __restrict__ Mt) {
  const int lane = threadIdx.x;
  const int ln = lane & 15, q = lane >> 4;
  const int m0 = blockIdx.y * 32;   // o rows of Mt
  const int n0 = blockIdx.x * 32;   // d cols of Mt
  const float* __restrict__ wv = w_qkv + 2 * 4 * DIM * 128;  // v slice

  f32x4 acc[2][2] = {};

#pragma unroll
  for (int k0 = 0; k0 < DIM; k0 += 32) {   // k = c = h*128+hd
    const int h = k0 >> 7, hb = k0 & 127;
    bf16x8 af[2], bf[2];
#pragma unroll
    for (int mi = 0; mi < 2; ++mi) {
      float raw[8];
#pragma unroll
      for (int j = 0; j < 8; ++j)
        raw[j] = w_proj[(k0 + q * 8 + j) * DIM + (m0 + mi * 16 + ln)];
#pragma unroll
      for (int j = 0; j < 8; ++j) af[mi][j] = (__bf16)raw[j];
    }
#pragma unroll
    for (int ni = 0; ni < 2; ++ni)
      bf[ni] = cvt8(&wv[((size_t)h * DIM + (n0 + ni * 16 + ln)) * 128 + hb + q * 8]);
#pragma unroll
    for (int mi = 0; mi < 2; ++mi)
#pragma unroll
      for (int ni = 0; ni < 2; ++ni)
        acc[mi][ni] = __builtin_amdgcn_mfma_f32_16x16x32_bf16(
            af[mi], bf[ni], acc[mi][ni], 0, 0, 0);
  }

  // D layout: col = lane&15, row = (lane>>4)*4 + reg
#pragma unroll
  for (int mi = 0; mi < 2; ++mi)
#pragma unroll
    for (int ni = 0; ni < 2; ++ni)
#pragma unroll
      for (int r = 0; r < 4; ++r) {
        const int o = m0 + mi * 16 + q * 4 + r;
        const int d = n0 + ni * 16 + ln;
        Mt[o * DIM + d] = (__bf16)(acc[mi][ni][r] * (float)NNODES);
      }
}

// ---------------------------------------------------------------------------
// Kernel 2: out[b][o] = sum_d xb[b][d] * Mt[o][d] + bias[o], fp32 out.
// 256 threads = 4 waves (2m x 2n); wave tile 32(b) x 64(o); block 64x128.
// Grid (512/128) x (4096/64) = 4 x 64 = 256 blocks, 8 waves/CU.
// Per wave K-iter: 2 + 4 = 6 x 16B loads, 8 MFMAs, zero cvt.
// ---------------------------------------------------------------------------
__global__ __launch_bounds__(256) void gemm_out(
    const __bf16* __restrict__ xb,
    const __bf16* __restrict__ Mt,
    const float* __restrict__ bias,
    float* __restrict__ out) {
  const int tid = threadIdx.x;
  const int wave = tid >> 6, lane = tid & 63;
  const int ln = lane & 15, q = lane >> 4;
  const int m0 = blockIdx.y * 64 + (wave >> 1) * 32;   // b rows
  const int n0 = blockIdx.x * 128 + (wave & 1) * 64;   // o cols

  f32x4 acc[2][4] = {};

#pragma unroll 4
  for (int k0 = 0; k0 < DIM; k0 += 32) {
    bf16x8 af[2], bf[4];
#pragma unroll
    for (int mi = 0; mi < 2; ++mi)
      af[mi] = *(const bf16x8*)&xb[(size_t)(m0 + mi * 16 + ln) * DIM + k0 + q * 8];
#pragma unroll
    for (int ni = 0; ni < 4; ++ni)
      bf[ni] = *(const bf16x8*)&Mt[(size_t)(n0 + ni * 16 + ln) * DIM + k0 + q * 8];
#pragma unroll
    for (int mi = 0; mi < 2; ++mi)
#pragma unroll
      for (int ni = 0; ni < 4; ++ni)
        acc[mi][ni] = __builtin_amdgcn_mfma_f32_16x16x32_bf16(
            af[mi], bf[ni], acc[mi][ni], 0, 0, 0);
  }

#pragma unroll
  for (int ni = 0; ni < 4; ++ni) {
    const int o = n0 + ni * 16 + ln;
    const float bj = bias[o];
#pragma unroll
    for (int mi = 0; mi < 2; ++mi)
#pragma unroll
      for (int r = 0; r < 4; ++r) {
        const int b = m0 + mi * 16 + q * 4 + r;
        out[(size_t)b * DIM + o] = acc[mi][ni][r] + bj;
      }
  }
}

extern "C" void kernel_launch(void* const* d_in, const int* in_sizes, int n_in,
                              void* d_out, int out_size, void* d_ws, size_t ws_size,
                              hipStream_t stream) {
  const float* x      = (const float*)d_in[0];
  // d_in[1] = adj — irrelevant (softmax rows sum to 1), never read
  const float* w_qkv  = (const float*)d_in[2];
  const float* w_proj = (const float*)d_in[3];
  const float* b_proj = (const float*)d_in[4];
  __bf16* Mt = (__bf16*)d_ws;                          // 512 KB
  __bf16* xb = (__bf16*)((char*)d_ws + DIM * DIM * 2); // 4 MB, 16B-aligned
  float* out = (float*)d_out;                          // 4096*512 fp32

  cvt_x<<<dim3(NNODES * DIM / (256 * 8)), 256, 0, stream>>>(x, xb);
  build_Mt<<<dim3(DIM / 32, DIM / 32), 64, 0, stream>>>(w_qkv, w_proj, Mt);
  gemm_out<<<dim3(DIM / 128, NNODES / 64), 256, 0, stream>>>(xb, Mt, b_proj, out);
}